// Round 1
// baseline (2023.855 us; speedup 1.0000x reference)
//
#include <hip/hip_runtime.h>

#define H 1024
#define MMEM 4096
#define NTOK 8192
#define KTOP 64
#define FTHRESH 0.5f

typedef short bfrag __attribute__((ext_vector_type(8)));   // 8 bf16 in 4 VGPRs
typedef float vf4  __attribute__((ext_vector_type(4)));    // MFMA f32 acc

__device__ __forceinline__ short f2bf(float x){
  union { float f; unsigned u; } a; a.f = x;
  unsigned r = a.u + 0x7fffu + ((a.u >> 16) & 1u);   // RNE
  return (short)(r >> 16);
}
__device__ __forceinline__ float bf2f(short s){
  union { float f; unsigned u; } a; a.u = ((unsigned)(unsigned short)s) << 16;
  return a.f;
}

// ---------------- LayerNorm + surprise + hi/lo split ----------------
__global__ __launch_bounds__(256) void ln_kernel(
    const float* __restrict__ hs, const float* __restrict__ g, const float* __restrict__ be,
    short* __restrict__ nh, short* __restrict__ nl, float* __restrict__ surprise)
{
  int row = blockIdx.x, tid = threadIdx.x;
  long base = (long)row * H;
  float4 x = ((const float4*)(hs + base))[tid];
  float s1 = x.x + x.y + x.z + x.w;
  float s2 = x.x*x.x + x.y*x.y + x.z*x.z + x.w*x.w;
  __shared__ float r1[4], r2[4], r3[4];
  int w = tid >> 6, lane = tid & 63;
  for (int o = 32; o; o >>= 1){ s1 += __shfl_down(s1, o); s2 += __shfl_down(s2, o); }
  if (lane == 0){ r1[w] = s1; r2[w] = s2; }
  __syncthreads();
  float S1 = r1[0]+r1[1]+r1[2]+r1[3];
  float S2 = r2[0]+r2[1]+r2[2]+r2[3];
  float mean = S1 * (1.0f/H);
  float var  = S2 * (1.0f/H) - mean*mean;
  float rinv = rsqrtf(var + 1e-12f);
  float4 gg = ((const float4*)g)[tid];
  float4 bb = ((const float4*)be)[tid];
  float n0 = (x.x-mean)*rinv*gg.x + bb.x;
  float n1 = (x.y-mean)*rinv*gg.y + bb.y;
  float n2 = (x.z-mean)*rinv*gg.z + bb.z;
  float n3 = (x.w-mean)*rinv*gg.w + bb.w;
  float sa = fabsf(n0)+fabsf(n1)+fabsf(n2)+fabsf(n3);
  for (int o = 32; o; o >>= 1) sa += __shfl_down(sa, o);
  if (lane == 0) r3[w] = sa;
  __syncthreads();
  if (tid == 0) surprise[row] = (r3[0]+r3[1]+r3[2]+r3[3]) * (1.0f/H);
  short4 h4, l4;
  h4.x = f2bf(n0); l4.x = f2bf(n0 - bf2f(h4.x));
  h4.y = f2bf(n1); l4.y = f2bf(n1 - bf2f(h4.y));
  h4.z = f2bf(n2); l4.z = f2bf(n2 - bf2f(h4.z));
  h4.w = f2bf(n3); l4.w = f2bf(n3 - bf2f(h4.w));
  ((short4*)(nh + base))[tid] = h4;
  ((short4*)(nl + base))[tid] = l4;
}

// ---------------- top-K (block0: max of surprise; block1: min of importance) ----------------
__global__ __launch_bounds__(256) void topk_kernel(
    const float* __restrict__ surprise, const float* __restrict__ imp,
    float* __restrict__ top_vals, int* __restrict__ top_idx, int* __restrict__ slots)
{
  __shared__ float v[NTOK];
  __shared__ float rv[256]; __shared__ int ri[256];
  int tid = threadIdx.x;
  int maxmode = (blockIdx.x == 0);
  int N = maxmode ? NTOK : MMEM;
  const float* src = maxmode ? surprise : imp;
  for (int i = tid; i < N; i += 256) v[i] = src[i];
  __syncthreads();
  for (int it = 0; it < KTOP; ++it){
    float best = maxmode ? -1e30f : 1e30f; int bi = 0x7fffffff;
    for (int i = tid; i < N; i += 256){
      float x = v[i];
      bool better = maxmode ? (x > best) : (x < best);   // strict => lowest idx on ties (stable)
      if (better){ best = x; bi = i; }
    }
    rv[tid] = best; ri[tid] = bi;
    __syncthreads();
    for (int s = 128; s; s >>= 1){
      if (tid < s){
        float ov = rv[tid+s]; int oi = ri[tid+s];
        bool better = maxmode ? (ov > rv[tid]) : (ov < rv[tid]);
        bool tie = (ov == rv[tid]) && (oi < ri[tid]);
        if (better || tie){ rv[tid] = ov; ri[tid] = oi; }
      }
      __syncthreads();
    }
    if (tid == 0){
      int idx = ri[0];
      if (maxmode){ top_vals[it] = rv[0]; top_idx[it] = idx; v[idx] = -1e30f; }
      else        { slots[it] = idx;                          v[idx] =  1e30f; }
    }
    __syncthreads();
  }
}

// ---------------- fp32 -> bf16 hi/lo split (elementwise, float4) ----------------
__global__ __launch_bounds__(256) void split_f32_kernel(
    const float* __restrict__ in, short* __restrict__ hi, short* __restrict__ lo)
{
  long i = (long)blockIdx.x * 256 + threadIdx.x;
  float4 x = ((const float4*)in)[i];
  short4 h, l;
  h.x = f2bf(x.x); l.x = f2bf(x.x - bf2f(h.x));
  h.y = f2bf(x.y); l.y = f2bf(x.y - bf2f(h.y));
  h.z = f2bf(x.z); l.z = f2bf(x.z - bf2f(h.z));
  h.w = f2bf(x.w); l.w = f2bf(x.w - bf2f(h.w));
  ((short4*)hi)[i] = h; ((short4*)lo)[i] = l;
}

__global__ __launch_bounds__(256) void tobf16_kernel(const float* __restrict__ in, short* __restrict__ out)
{
  long i = (long)blockIdx.x * 256 + threadIdx.x;
  float4 x = ((const float4*)in)[i];
  short4 h;
  h.x = f2bf(x.x); h.y = f2bf(x.y); h.z = f2bf(x.z); h.w = f2bf(x.w);
  ((short4*)out)[i] = h;
}

// ---------------- Wq (fp32 [H][H]) -> WqT hi/lo bf16 [H][H] ----------------
__global__ __launch_bounds__(256) void transpose_split_kernel(
    const float* __restrict__ in, short* __restrict__ th_, short* __restrict__ tl_)
{
  __shared__ float t[32][33];
  int c0 = blockIdx.x*32, r0 = blockIdx.y*32;
  int tid = threadIdx.x;
  for (int k = 0; k < 4; ++k){
    int i = tid + k*256; int r = i >> 5, c = i & 31;
    t[r][c] = in[(long)(r0+r)*H + c0 + c];
  }
  __syncthreads();
  for (int k = 0; k < 4; ++k){
    int i = tid + k*256; int c = i >> 5, r = i & 31;
    float x = t[r][c];
    short hh = f2bf(x);
    th_[(long)(c0+c)*H + r0 + r] = hh;
    tl_[(long)(c0+c)*H + r0 + r] = f2bf(x - bf2f(hh));
  }
}

// ---------------- apply top-K surprise writes into mem hi/lo copies ----------------
__global__ __launch_bounds__(256) void update_kernel(
    const float* __restrict__ top_vals, const int* __restrict__ top_idx, const int* __restrict__ slots,
    const short* __restrict__ nh, const short* __restrict__ nl,
    short* __restrict__ mh, short* __restrict__ ml)
{
  int i = blockIdx.x;
  if (top_vals[i] <= FTHRESH) return;
  int s = slots[i], r = top_idx[i];
  long so = (long)s*H, ro = (long)r*H;
  for (int h = threadIdx.x; h < H; h += 256){ mh[so+h] = nh[ro+h]; ml[so+h] = nl[ro+h]; }
}

// ---------------- bf16 transpose mem_hi [MMEM][H] -> memT [H][MMEM] ----------------
__global__ __launch_bounds__(256) void transpose_bf16_kernel(const short* __restrict__ in, short* __restrict__ out)
{
  __shared__ short t[64][65];
  int r0 = blockIdx.y*64, c0 = blockIdx.x*64;
  int tid = threadIdx.x;
  for (int k = 0; k < 16; ++k){
    int i = tid + k*256; int r = i >> 6, c = i & 63;
    t[r][c] = in[(long)(r0+r)*H + c0 + c];
  }
  __syncthreads();
  for (int k = 0; k < 16; ++k){
    int i = tid + k*256; int c = i >> 6, r = i & 63;
    out[(long)(c0+c)*MMEM + r0 + r] = t[r][c];
  }
}

// ---------------- bias_m = bq . mem_m (fp32 exact from hi+lo) ----------------
__global__ __launch_bounds__(256) void bias_kernel(
    const float* __restrict__ bq, const short* __restrict__ mh, const short* __restrict__ ml,
    float* __restrict__ biasM)
{
  int tid = threadIdx.x, w = tid >> 6, lane = tid & 63;
  int m = blockIdx.x*4 + w;
  const short* ph = mh + (long)m*H;
  const short* pl = ml + (long)m*H;
  float s = 0.f;
  for (int j = 0; j < 16; ++j){
    int h = lane + j*64;
    s += bq[h] * (bf2f(ph[h]) + bf2f(pl[h]));
  }
  for (int o = 32; o; o >>= 1) s += __shfl_down(s, o);
  if (lane == 0) biasM[m] = s;
}

// ---------------- GEMM C[M][N] = A[M][K] * Bt[N][K]^T, bf16 MFMA, optional hi/lo split ----------------
// SPLIT=1: 3-term compensated (A_hi*B_hi + A_hi*B_lo + A_lo*B_hi), EPI=0: write C as hi/lo bf16
// SPLIT=0: plain bf16, EPI=1: C = acc + resid + biasN (fp32 out)
template<int SPLIT, int EPI>
__global__ __launch_bounds__(256) void gemm_bt_kernel(
    const short* __restrict__ Ah, const short* __restrict__ Al,
    const short* __restrict__ Bh, const short* __restrict__ Bl,
    int K, int N,
    short* __restrict__ Chi, short* __restrict__ Clo,
    float* __restrict__ Cout, const float* __restrict__ resid, const float* __restrict__ biasN)
{
  __shared__ short sAh[64*72], sBh[64*72];
  __shared__ short sAl[SPLIT ? 64*72 : 1], sBl[SPLIT ? 64*72 : 1];
  int tid = threadIdx.x;
  int w = tid >> 6, lane = tid & 63, ln = lane & 15, quad = lane >> 4;
  long m0 = (long)blockIdx.y * 64, n0 = (long)blockIdx.x * 64;
  vf4 acc[4];
  for (int i = 0; i < 4; ++i) for (int r = 0; r < 4; ++r) acc[i][r] = 0.0f;

  for (int kk = 0; kk < K; kk += 64){
    #pragma unroll
    for (int i = 0; i < 2; ++i){
      int c = tid + i*256; int row = c >> 3, c8 = c & 7;
      *(uint4*)&sAh[row*72 + c8*8] = *(const uint4*)&Ah[(m0+row)*K + kk + c8*8];
      *(uint4*)&sBh[row*72 + c8*8] = *(const uint4*)&Bh[(n0+row)*K + kk + c8*8];
      if (SPLIT){
        *(uint4*)&sAl[row*72 + c8*8] = *(const uint4*)&Al[(m0+row)*K + kk + c8*8];
        *(uint4*)&sBl[row*72 + c8*8] = *(const uint4*)&Bl[(n0+row)*K + kk + c8*8];
      }
    }
    __syncthreads();
    #pragma unroll
    for (int ks = 0; ks < 64; ks += 32){
      bfrag bh = *(const bfrag*)&sBh[(w*16+ln)*72 + ks + quad*8];
      bfrag bl;
      if (SPLIT) bl = *(const bfrag*)&sBl[(w*16+ln)*72 + ks + quad*8];
      #pragma unroll
      for (int i = 0; i < 4; ++i){
        bfrag ah = *(const bfrag*)&sAh[(i*16+ln)*72 + ks + quad*8];
        acc[i] = __builtin_amdgcn_mfma_f32_16x16x32_bf16(ah, bh, acc[i], 0, 0, 0);
        if (SPLIT){
          bfrag al = *(const bfrag*)&sAl[(i*16+ln)*72 + ks + quad*8];
          acc[i] = __builtin_amdgcn_mfma_f32_16x16x32_bf16(ah, bl, acc[i], 0, 0, 0);
          acc[i] = __builtin_amdgcn_mfma_f32_16x16x32_bf16(al, bh, acc[i], 0, 0, 0);
        }
      }
    }
    __syncthreads();
  }
  #pragma unroll
  for (int i = 0; i < 4; ++i){
    #pragma unroll
    for (int r = 0; r < 4; ++r){
      long row = m0 + i*16 + quad*4 + r;    // C/D: row = quad*4+reg, col = lane&15  [m89/m91]
      long col = n0 + w*16 + ln;
      float vv = acc[i][r];
      if (EPI == 0){
        short hh = f2bf(vv);
        Chi[row*N + col] = hh;
        Clo[row*N + col] = f2bf(vv - bf2f(hh));
      } else {
        Cout[row*N + col] = vv + resid[row*N + col] + biasN[col];
      }
    }
  }
}

// ---------------- fused flash attention over memory ----------------
// 32 tokens/block, 512 threads (8 waves: th = w&1 token-half, wg = w>>1 col/h group)
// sim: split-bf16 3-MFMA; softmax fp32 online; PV plain bf16 from memT staged in LDS
__global__ __launch_bounds__(512) void flash_kernel(
    const short* __restrict__ nh, const short* __restrict__ nl,
    const short* __restrict__ W2h, const short* __restrict__ W2l,
    const short* __restrict__ memT, const float* __restrict__ biasM,
    short* __restrict__ retr)
{
  extern __shared__ char smem[];
  short* An_hi = (short*)smem;                // [32][264]
  short* An_lo = An_hi + 32*264;
  short* Bw_hi = An_lo + 32*264;              // [64][264]
  short* Bw_lo = Bw_hi + 64*264;              // sim staging ends @ 101,376 B
  short* Vt    = (short*)smem;                // UNION: [1024][72] = 147,456 B
  short* Pb    = (short*)(smem + 147456);     // [32][72]
  float* m_sh  = (float*)(smem + 152064);     // 32
  float* l_sh  = m_sh + 32;
  float* al_sh = m_sh + 64;
  float* mn_sh = m_sh + 96;
  float* pm    = m_sh + 128;                  // [4][32]
  float* ps    = m_sh + 256;                  // [4][32]

  int tid = threadIdx.x;
  int w = tid >> 6, lane = tid & 63, ln = lane & 15, quad = lane >> 4;
  int th = w & 1, wg = w >> 1;
  long t0 = (long)blockIdx.x * 32;

  vf4 o_acc[16];
  #pragma unroll
  for (int t = 0; t < 16; ++t) for (int r = 0; r < 4; ++r) o_acc[t][r] = 0.0f;
  if (tid < 32){ m_sh[tid] = -1e30f; l_sh[tid] = 0.0f; }
  __syncthreads();

  for (int mc = 0; mc < MMEM; mc += 64){
    float bias_v = biasM[mc + wg*16 + ln];
    vf4 acc; for (int r = 0; r < 4; ++r) acc[r] = bias_v;

    for (int kk = 0; kk < H; kk += 256){
      #pragma unroll
      for (int i = 0; i < 2; ++i){
        int c = tid + i*512; int row = c >> 5, c8 = c & 31;
        *(uint4*)&An_hi[row*264 + c8*8] = *(const uint4*)&nh[(t0+row)*H + kk + c8*8];
        *(uint4*)&An_lo[row*264 + c8*8] = *(const uint4*)&nl[(t0+row)*H + kk + c8*8];
      }
      #pragma unroll
      for (int i = 0; i < 4; ++i){
        int c = tid + i*512; int row = c >> 5, c8 = c & 31;
        *(uint4*)&Bw_hi[row*264 + c8*8] = *(const uint4*)&W2h[(long)(mc+row)*H + kk + c8*8];
        *(uint4*)&Bw_lo[row*264 + c8*8] = *(const uint4*)&W2l[(long)(mc+row)*H + kk + c8*8];
      }
      __syncthreads();
      #pragma unroll
      for (int ks = 0; ks < 256; ks += 32){
        bfrag ah = *(const bfrag*)&An_hi[(th*16+ln)*264 + ks + quad*8];
        bfrag al = *(const bfrag*)&An_lo[(th*16+ln)*264 + ks + quad*8];
        bfrag bh = *(const bfrag*)&Bw_hi[(wg*16+ln)*264 + ks + quad*8];
        bfrag bl = *(const bfrag*)&Bw_lo[(wg*16+ln)*264 + ks + quad*8];
        acc = __builtin_amdgcn_mfma_f32_16x16x32_bf16(ah, bh, acc, 0, 0, 0);
        acc = __builtin_amdgcn_mfma_f32_16x16x32_bf16(ah, bl, acc, 0, 0, 0);
        acc = __builtin_amdgcn_mfma_f32_16x16x32_bf16(al, bh, acc, 0, 0, 0);
      }
      __syncthreads();
    }

    // ---- online softmax update (fp32 exact) ----
    float mx[4];
    #pragma unroll
    for (int j = 0; j < 4; ++j){
      float v = acc[j];
      for (int o = 1; o < 16; o <<= 1) v = fmaxf(v, __shfl_xor(v, o));
      mx[j] = v;
    }
    if (ln == 0){
      #pragma unroll
      for (int j = 0; j < 4; ++j) pm[wg*32 + th*16 + quad*4 + j] = mx[j];
    }
    __syncthreads();
    if (tid < 32){
      float cm = fmaxf(fmaxf(pm[tid], pm[32+tid]), fmaxf(pm[64+tid], pm[96+tid]));
      float mo = m_sh[tid];
      float mn = fmaxf(mo, cm);
      m_sh[tid] = mn; mn_sh[tid] = mn;
      al_sh[tid] = expf(mo - mn);
    }
    __syncthreads();
    #pragma unroll
    for (int j = 0; j < 4; ++j){
      int tok = th*16 + quad*4 + j;
      float p = expf(acc[j] - mn_sh[tok]);
      Pb[tok*72 + wg*16 + ln] = f2bf(p);
      float s = p;
      for (int o = 1; o < 16; o <<= 1) s += __shfl_xor(s, o);
      if (ln == 0) ps[wg*32 + tok] = s;
    }
    {
      float ar[4];
      #pragma unroll
      for (int r = 0; r < 4; ++r) ar[r] = al_sh[th*16 + quad*4 + r];
      #pragma unroll
      for (int t = 0; t < 16; ++t)
        for (int r = 0; r < 4; ++r) o_acc[t][r] *= ar[r];
    }
    __syncthreads();
    if (tid < 32) l_sh[tid] = l_sh[tid]*al_sh[tid] + ps[tid] + ps[32+tid] + ps[64+tid] + ps[96+tid];

    // ---- stage memT chunk [1024 h][64 m] and accumulate O += P*V ----
    #pragma unroll
    for (int i = 0; i < 16; ++i){
      int c = tid + i*512; int h = c >> 3, m8 = c & 7;
      *(uint4*)&Vt[h*72 + m8*8] = *(const uint4*)&memT[(long)h*MMEM + mc + m8*8];
    }
    __syncthreads();
    bfrag p0 = *(const bfrag*)&Pb[(th*16+ln)*72 + quad*8];
    bfrag p1 = *(const bfrag*)&Pb[(th*16+ln)*72 + 32 + quad*8];
    #pragma unroll
    for (int t = 0; t < 16; ++t){
      const short* vb = &Vt[(wg*256 + t*16 + ln)*72];
      bfrag b0 = *(const bfrag*)&vb[quad*8];
      bfrag b1 = *(const bfrag*)&vb[32 + quad*8];
      o_acc[t] = __builtin_amdgcn_mfma_f32_16x16x32_bf16(p0, b0, o_acc[t], 0, 0, 0);
      o_acc[t] = __builtin_amdgcn_mfma_f32_16x16x32_bf16(p1, b1, o_acc[t], 0, 0, 0);
    }
    __syncthreads();   // protect union region before next chunk's staging
  }

  float linv[4];
  #pragma unroll
  for (int r = 0; r < 4; ++r) linv[r] = 1.0f / l_sh[th*16 + quad*4 + r];
  #pragma unroll
  for (int t = 0; t < 16; ++t){
    long col = wg*256 + t*16 + ln;
    #pragma unroll
    for (int r = 0; r < 4; ++r){
      long row = t0 + th*16 + quad*4 + r;
      retr[row*H + col] = f2bf(o_acc[t][r] * linv[r]);
    }
  }
}

extern "C" void kernel_launch(void* const* d_in, const int* in_sizes, int n_in,
                              void* d_out, int out_size, void* d_ws, size_t ws_size,
                              hipStream_t stream)
{
  const float* hs  = (const float*)d_in[0];
  const float* gam = (const float*)d_in[1];
  const float* bet = (const float*)d_in[2];
  const float* Wq  = (const float*)d_in[3];
  const float* bq  = (const float*)d_in[4];
  const float* Wo  = (const float*)d_in[5];
  const float* bo  = (const float*)d_in[6];
  const float* mem = (const float*)d_in[7];
  const float* imp = (const float*)d_in[8];
  float* out = (float*)d_out;

  char* ws = (char*)d_ws;
  short* nh    = (short*)(ws);                         // 16 MB  norm hi
  short* nl    = (short*)(ws + (16ull<<20));           // 16 MB  norm lo
  short* mh    = (short*)(ws + (32ull<<20));           // 8 MB   mem hi (updated)
  short* ml    = (short*)(ws + (40ull<<20));           // 8 MB   mem lo (updated)
  short* memT  = (short*)(ws + (48ull<<20));           // 8 MB   mem^T hi
  short* wqt_h = (short*)(ws + (56ull<<20));           // 2 MB
  short* wqt_l = (short*)(ws + (58ull<<20));           // 2 MB
  short* wo_b  = (short*)(ws + (60ull<<20));           // 2 MB
  short* w2h   = (short*)(ws + (62ull<<20));           // 8 MB   W2 = mem@Wq hi
  short* w2l   = (short*)(ws + (70ull<<20));           // 8 MB
  short* retr  = (short*)(ws + (78ull<<20));           // 16 MB  retrieved bf16
  float* biasM    = (float*)(ws + (94ull<<20));                  // 16 KB
  float* surprise = (float*)(ws + (94ull<<20) + (64ull<<10));    // 32 KB
  float* top_vals = (float*)(ws + (94ull<<20) + (128ull<<10));
  int*   top_idx  = (int*)  (ws + (94ull<<20) + (129ull<<10));
  int*   slots    = (int*)  (ws + (94ull<<20) + (130ull<<10));

  ln_kernel<<<NTOK, 256, 0, stream>>>(hs, gam, bet, nh, nl, surprise);
  topk_kernel<<<2, 256, 0, stream>>>(surprise, imp, top_vals, top_idx, slots);
  split_f32_kernel<<<4096, 256, 0, stream>>>(mem, mh, ml);
  transpose_split_kernel<<<dim3(32,32), 256, 0, stream>>>(Wq, wqt_h, wqt_l);
  tobf16_kernel<<<1024, 256, 0, stream>>>(Wo, wo_b);
  update_kernel<<<KTOP, 256, 0, stream>>>(top_vals, top_idx, slots, nh, nl, mh, ml);
  transpose_bf16_kernel<<<dim3(16,64), 256, 0, stream>>>(mh, memT);
  bias_kernel<<<1024, 256, 0, stream>>>(bq, mh, ml, biasM);
  // W2 = mem_upd @ Wq  (split-compensated), output split hi/lo
  gemm_bt_kernel<1,0><<<dim3(16,64), 256, 0, stream>>>(
      mh, ml, wqt_h, wqt_l, H, H, w2h, w2l, nullptr, nullptr, nullptr);
  // fused attention
  hipFuncSetAttribute((const void*)flash_kernel, hipFuncAttributeMaxDynamicSharedMemorySize, 153600);
  flash_kernel<<<NTOK/32, 512, 153600, stream>>>(nh, nl, w2h, w2l, memT, biasM, retr);
  // out = hidden + retr @ Wo^T + bo
  gemm_bt_kernel<0,1><<<dim3(16,128), 256, 0, stream>>>(
      retr, retr, wo_b, wo_b, H, H, nullptr, nullptr, out, hs, bo);
}

// Round 2
// 592.753 us; speedup vs baseline: 3.4143x; 3.4143x over previous
//
#include <hip/hip_runtime.h>

#define H 1024
#define MMEM 4096
#define NTOK 8192
#define KTOP 64
#define FTHRESH 0.5f

typedef short bfrag __attribute__((ext_vector_type(8)));   // 8 bf16 in 4 VGPRs
typedef float vf4  __attribute__((ext_vector_type(4)));    // MFMA f32 acc
typedef short short8v __attribute__((ext_vector_type(8)));
typedef _Float16 half8 __attribute__((ext_vector_type(8)));

__device__ __forceinline__ short f2bf(float x){
  union { float f; unsigned u; } a; a.f = x;
  unsigned r = a.u + 0x7fffu + ((a.u >> 16) & 1u);   // RNE
  return (short)(r >> 16);
}
__device__ __forceinline__ float bf2f(short s){
  union { float f; unsigned u; } a; a.u = ((unsigned)(unsigned short)s) << 16;
  return a.f;
}
__device__ __forceinline__ short f2h(float x){
  union { _Float16 h; short s; } u; u.h = (_Float16)x; return u.s;
}

// async global->LDS, 16B per lane; lds ptr must be wave-uniform (HW adds lane*16)
__device__ __forceinline__ void gload_lds16(const short* g, short* l){
  __builtin_amdgcn_global_load_lds(
      (const __attribute__((address_space(1))) unsigned int*)g,
      (__attribute__((address_space(3))) unsigned int*)l, 16, 0, 0);
}

// ---------------- LayerNorm + surprise + hi/lo split ----------------
__global__ __launch_bounds__(256) void ln_kernel(
    const float* __restrict__ hs, const float* __restrict__ g, const float* __restrict__ be,
    short* __restrict__ nh, short* __restrict__ nl, float* __restrict__ surprise)
{
  int row = blockIdx.x, tid = threadIdx.x;
  long base = (long)row * H;
  float4 x = ((const float4*)(hs + base))[tid];
  float s1 = x.x + x.y + x.z + x.w;
  float s2 = x.x*x.x + x.y*x.y + x.z*x.z + x.w*x.w;
  __shared__ float r1[4], r2[4], r3[4];
  int w = tid >> 6, lane = tid & 63;
  for (int o = 32; o; o >>= 1){ s1 += __shfl_down(s1, o); s2 += __shfl_down(s2, o); }
  if (lane == 0){ r1[w] = s1; r2[w] = s2; }
  __syncthreads();
  float S1 = r1[0]+r1[1]+r1[2]+r1[3];
  float S2 = r2[0]+r2[1]+r2[2]+r2[3];
  float mean = S1 * (1.0f/H);
  float var  = S2 * (1.0f/H) - mean*mean;
  float rinv = rsqrtf(var + 1e-12f);
  float4 gg = ((const float4*)g)[tid];
  float4 bb = ((const float4*)be)[tid];
  float n0 = (x.x-mean)*rinv*gg.x + bb.x;
  float n1 = (x.y-mean)*rinv*gg.y + bb.y;
  float n2 = (x.z-mean)*rinv*gg.z + bb.z;
  float n3 = (x.w-mean)*rinv*gg.w + bb.w;
  float sa = fabsf(n0)+fabsf(n1)+fabsf(n2)+fabsf(n3);
  for (int o = 32; o; o >>= 1) sa += __shfl_down(sa, o);
  if (lane == 0) r3[w] = sa;
  __syncthreads();
  if (tid == 0) surprise[row] = (r3[0]+r3[1]+r3[2]+r3[3]) * (1.0f/H);
  short4 h4, l4;
  h4.x = f2bf(n0); l4.x = f2bf(n0 - bf2f(h4.x));
  h4.y = f2bf(n1); l4.y = f2bf(n1 - bf2f(h4.y));
  h4.z = f2bf(n2); l4.z = f2bf(n2 - bf2f(h4.z));
  h4.w = f2bf(n3); l4.w = f2bf(n3 - bf2f(h4.w));
  ((short4*)(nh + base))[tid] = h4;
  ((short4*)(nl + base))[tid] = l4;
}

// ---------------- register-resident top-K selection ----------------
// block 0: top-K of surprise (max, ties->lower idx). block 1: K smallest importance.
__global__ __launch_bounds__(256) void topk_kernel(
    const float* __restrict__ surprise, const float* __restrict__ imp,
    float* __restrict__ top_vals, int* __restrict__ top_idx, int* __restrict__ slots)
{
  int tid = threadIdx.x, w = tid >> 6, lane = tid & 63;
  int maxmode = (blockIdx.x == 0);
  int per = maxmode ? 32 : 16;
  const float* src = maxmode ? surprise : imp;
  float v[32];
  unsigned mask = maxmode ? 0xffffffffu : 0xffffu;
  #pragma unroll
  for (int j = 0; j < 32; ++j)
    if (j < per){ float x = src[tid + j*256]; v[j] = maxmode ? x : -x; }

  __shared__ float wv[4]; __shared__ int wi[4]; __shared__ int pub;
  for (int it = 0; it < KTOP; ++it){
    float best = -1e30f; int bi = 0x7fffffff;
    #pragma unroll
    for (int j = 0; j < 32; ++j){
      if (mask & (1u << j)){
        float x = v[j];
        if (x > best){ best = x; bi = tid + j*256; }   // ascending idx within thread
      }
    }
    for (int o = 32; o; o >>= 1){
      float ov = __shfl_down(best, o); int oi = __shfl_down(bi, o);
      if (ov > best || (ov == best && oi < bi)){ best = ov; bi = oi; }
    }
    if (lane == 0){ wv[w] = best; wi[w] = bi; }
    __syncthreads();
    if (tid == 0){
      float b = wv[0]; int bidx = wi[0];
      for (int q = 1; q < 4; ++q)
        if (wv[q] > b || (wv[q] == b && wi[q] < bidx)){ b = wv[q]; bidx = wi[q]; }
      if (maxmode){ top_vals[it] = b; top_idx[it] = bidx; }
      else slots[it] = bidx;
      pub = bidx;
    }
    __syncthreads();
    int widx = pub;
    if ((widx & 255) == tid) mask &= ~(1u << (widx >> 8));
  }
}

// ---------------- fp32 -> bf16 hi/lo split ----------------
__global__ __launch_bounds__(256) void split_f32_kernel(
    const float* __restrict__ in, short* __restrict__ hi, short* __restrict__ lo)
{
  long i = (long)blockIdx.x * 256 + threadIdx.x;
  float4 x = ((const float4*)in)[i];
  short4 h, l;
  h.x = f2bf(x.x); l.x = f2bf(x.x - bf2f(h.x));
  h.y = f2bf(x.y); l.y = f2bf(x.y - bf2f(h.y));
  h.z = f2bf(x.z); l.z = f2bf(x.z - bf2f(h.z));
  h.w = f2bf(x.w); l.w = f2bf(x.w - bf2f(h.w));
  ((short4*)hi)[i] = h; ((short4*)lo)[i] = l;
}

__global__ __launch_bounds__(256) void tobf16_kernel(const float* __restrict__ in, short* __restrict__ out)
{
  long i = (long)blockIdx.x * 256 + threadIdx.x;
  float4 x = ((const float4*)in)[i];
  short4 h;
  h.x = f2bf(x.x); h.y = f2bf(x.y); h.z = f2bf(x.z); h.w = f2bf(x.w);
  ((short4*)out)[i] = h;
}

// ---------------- Wq fp32 [H][H] -> WqT hi/lo bf16 ----------------
__global__ __launch_bounds__(256) void transpose_split_kernel(
    const float* __restrict__ in, short* __restrict__ th_, short* __restrict__ tl_)
{
  __shared__ float t[32][33];
  int c0 = blockIdx.x*32, r0 = blockIdx.y*32;
  int tid = threadIdx.x;
  for (int k = 0; k < 4; ++k){
    int i = tid + k*256; int r = i >> 5, c = i & 31;
    t[r][c] = in[(long)(r0+r)*H + c0 + c];
  }
  __syncthreads();
  for (int k = 0; k < 4; ++k){
    int i = tid + k*256; int c = i >> 5, r = i & 31;
    float x = t[r][c];
    short hh = f2bf(x);
    th_[(long)(c0+c)*H + r0 + r] = hh;
    tl_[(long)(c0+c)*H + r0 + r] = f2bf(x - bf2f(hh));
  }
}

// ---------------- apply top-K surprise writes ----------------
__global__ __launch_bounds__(256) void update_kernel(
    const float* __restrict__ top_vals, const int* __restrict__ top_idx, const int* __restrict__ slots,
    const short* __restrict__ nh, const short* __restrict__ nl,
    short* __restrict__ mh, short* __restrict__ ml)
{
  int i = blockIdx.x;
  if (top_vals[i] <= FTHRESH) return;
  int s = slots[i], r = top_idx[i];
  long so = (long)s*H, ro = (long)r*H;
  for (int h = threadIdx.x; h < H; h += 256){ mh[so+h] = nh[ro+h]; ml[so+h] = nl[ro+h]; }
}

// ---------------- bf16 transpose mem_hi [MMEM][H] -> memT [H][MMEM] ----------------
__global__ __launch_bounds__(256) void transpose_bf16_kernel(const short* __restrict__ in, short* __restrict__ out)
{
  __shared__ short t[64][65];
  int r0 = blockIdx.y*64, c0 = blockIdx.x*64;
  int tid = threadIdx.x;
  for (int k = 0; k < 16; ++k){
    int i = tid + k*256; int r = i >> 6, c = i & 63;
    t[r][c] = in[(long)(r0+r)*H + c0 + c];
  }
  __syncthreads();
  for (int k = 0; k < 16; ++k){
    int i = tid + k*256; int c = i >> 6, r = i & 63;
    out[(long)(c0+c)*MMEM + r0 + r] = t[r][c];
  }
}

// ---------------- biasM[m] = bq . mem_upd[m] ----------------
__global__ __launch_bounds__(256) void bias_kernel(
    const float* __restrict__ bq, const short* __restrict__ mh, const short* __restrict__ ml,
    float* __restrict__ biasM)
{
  int tid = threadIdx.x, w = tid >> 6, lane = tid & 63;
  int m = blockIdx.x*4 + w;
  const short* ph = mh + (long)m*H;
  const short* pl = ml + (long)m*H;
  float s = 0.f;
  for (int j = 0; j < 16; ++j){
    int h = lane + j*64;
    s += bq[h] * (bf2f(ph[h]) + bf2f(pl[h]));
  }
  for (int o = 32; o; o >>= 1) s += __shfl_down(s, o);
  if (lane == 0) biasM[m] = s;
}

// ---------------- 128x128-tile GEMM: C[M][N] = A[M][K] * B[N][K]^T ----------------
// m97 recipe: BK=64, global_load_lds w16, 2 barriers per K-block.
// SPLIT=1: 3-MFMA compensated (Ah*Bh + Ah*Bl + Al*Bh).
// MODE 0: C -> hi/lo bf16.  1: C+biasN -> fp16.  2: C -> bf16.  3: C+resid+biasN -> fp32.
template<int SPLIT, int MODE>
__global__ __launch_bounds__(256) void gemm128(
    const short* __restrict__ Ah, const short* __restrict__ Al,
    const short* __restrict__ Bh, const short* __restrict__ Bl,
    int K, int N,
    short* __restrict__ O1, short* __restrict__ O2,
    float* __restrict__ Of, const float* __restrict__ resid, const float* __restrict__ biasN)
{
  __shared__ short sAh[128*64];
  __shared__ short sBh[128*64];
  __shared__ short sAl[SPLIT ? 128*64 : 64];
  __shared__ short sBl[SPLIT ? 128*64 : 64];
  int tid = threadIdx.x, w = tid >> 6, lane = tid & 63, ln = lane & 15, quad = lane >> 4;
  int wr = w >> 1, wc = w & 1;
  long m0 = (long)blockIdx.y * 128, n0 = (long)blockIdx.x * 128;
  long Kl = K;
  vf4 acc[4][4];
  #pragma unroll
  for (int i = 0; i < 4; ++i) for (int j = 0; j < 4; ++j) for (int r = 0; r < 4; ++r) acc[i][j][r] = 0.0f;

  for (long kk = 0; kk < Kl; kk += 64){
    #pragma unroll
    for (int j = 0; j < 4; ++j){
      int f = (w*4 + j)*64 + lane;          // 16B chunk id in [0,1024)
      int row = f >> 3, c8 = f & 7;
      long go = kk + c8*8;
      short* dst = (short*)0;
      gload_lds16(Ah + (m0+row)*Kl + go, sAh + (w*4+j)*512);
      gload_lds16(Bh + (n0+row)*Kl + go, sBh + (w*4+j)*512);
      if (SPLIT){
        gload_lds16(Al + (m0+row)*Kl + go, sAl + (w*4+j)*512);
        gload_lds16(Bl + (n0+row)*Kl + go, sBl + (w*4+j)*512);
      }
      (void)dst;
    }
    __syncthreads();
    #pragma unroll
    for (int ks = 0; ks < 64; ks += 32){
      bfrag bh[4], bl[4];
      #pragma unroll
      for (int j = 0; j < 4; ++j){
        bh[j] = *(const bfrag*)&sBh[(wc*64 + j*16 + ln)*64 + ks + quad*8];
        if (SPLIT) bl[j] = *(const bfrag*)&sBl[(wc*64 + j*16 + ln)*64 + ks + quad*8];
      }
      #pragma unroll
      for (int i = 0; i < 4; ++i){
        bfrag ah = *(const bfrag*)&sAh[(wr*64 + i*16 + ln)*64 + ks + quad*8];
        #pragma unroll
        for (int j = 0; j < 4; ++j)
          acc[i][j] = __builtin_amdgcn_mfma_f32_16x16x32_bf16(ah, bh[j], acc[i][j], 0, 0, 0);
        if (SPLIT){
          bfrag al = *(const bfrag*)&sAl[(wr*64 + i*16 + ln)*64 + ks + quad*8];
          #pragma unroll
          for (int j = 0; j < 4; ++j){
            acc[i][j] = __builtin_amdgcn_mfma_f32_16x16x32_bf16(ah, bl[j], acc[i][j], 0, 0, 0);
            acc[i][j] = __builtin_amdgcn_mfma_f32_16x16x32_bf16(al, bh[j], acc[i][j], 0, 0, 0);
          }
        }
      }
    }
    __syncthreads();
  }

  #pragma unroll
  for (int i = 0; i < 4; ++i){
    #pragma unroll
    for (int j = 0; j < 4; ++j){
      #pragma unroll
      for (int r = 0; r < 4; ++r){
        long row = m0 + wr*64 + i*16 + quad*4 + r;   // C/D: row=quad*4+reg, col=lane&15
        long col = n0 + wc*64 + j*16 + ln;
        float v = acc[i][j][r];
        if (MODE == 0){
          short hh = f2bf(v);
          O1[row*(long)N + col] = hh;
          O2[row*(long)N + col] = f2bf(v - bf2f(hh));
        } else if (MODE == 1){
          O1[row*(long)N + col] = f2h(v + biasN[col]);
        } else if (MODE == 2){
          O1[row*(long)N + col] = f2bf(v);
        } else {
          Of[row*(long)N + col] = v + resid[row*(long)N + col] + biasN[col];
        }
      }
    }
  }
}

// ---------------- row softmax: sim fp16 [NTOK][MMEM] -> P bf16 (normalized) ----------------
__global__ __launch_bounds__(256) void softmax_kernel(
    const short* __restrict__ simh, short* __restrict__ P)
{
  long row = blockIdx.x;
  int tid = threadIdx.x, w = tid >> 6, lane = tid & 63;
  const half8* src = (const half8*)(simh + row*MMEM);
  float xf[16];
  float mx = -1e30f;
  #pragma unroll
  for (int j = 0; j < 2; ++j){
    half8 x = src[tid + j*256];
    #pragma unroll
    for (int e = 0; e < 8; ++e){ float f = (float)x[e]; xf[j*8+e] = f; mx = fmaxf(mx, f); }
  }
  for (int o = 32; o; o >>= 1) mx = fmaxf(mx, __shfl_xor(mx, o));
  __shared__ float rmax[4], rsum[4];
  if (lane == 0) rmax[w] = mx;
  __syncthreads();
  mx = fmaxf(fmaxf(rmax[0], rmax[1]), fmaxf(rmax[2], rmax[3]));
  float p[16], s = 0.f;
  #pragma unroll
  for (int k = 0; k < 16; ++k){ p[k] = __expf(xf[k] - mx); s += p[k]; }
  for (int o = 32; o; o >>= 1) s += __shfl_xor(s, o);
  if (lane == 0) rsum[w] = s;
  __syncthreads();
  float inv = 1.0f / (rsum[0]+rsum[1]+rsum[2]+rsum[3]);
  short8v* dst = (short8v*)(P + row*MMEM);
  #pragma unroll
  for (int j = 0; j < 2; ++j){
    short8v o8;
    #pragma unroll
    for (int e = 0; e < 8; ++e) o8[e] = f2bf(p[j*8+e] * inv);
    dst[tid + j*256] = o8;
  }
}

extern "C" void kernel_launch(void* const* d_in, const int* in_sizes, int n_in,
                              void* d_out, int out_size, void* d_ws, size_t ws_size,
                              hipStream_t stream)
{
  const float* hs  = (const float*)d_in[0];
  const float* gam = (const float*)d_in[1];
  const float* bet = (const float*)d_in[2];
  const float* Wq  = (const float*)d_in[3];
  const float* bq  = (const float*)d_in[4];
  const float* Wo  = (const float*)d_in[5];
  const float* bo  = (const float*)d_in[6];
  const float* mem = (const float*)d_in[7];
  const float* imp = (const float*)d_in[8];
  float* out = (float*)d_out;

  char* ws = (char*)d_ws;
  short* nh    = (short*)(ws);                   // [0,16) MB   dead after sim GEMM
  short* nl    = (short*)(ws + (16ull<<20));     // [16,32)     dead after sim GEMM
  short* mh    = (short*)(ws + (32ull<<20));     // [32,40)     dead after W2/bias/memT
  short* ml    = (short*)(ws + (40ull<<20));     // [40,48)
  short* w2h   = (short*)(ws + (48ull<<20));     // [48,56)     dead after sim GEMM
  short* w2l   = (short*)(ws + (56ull<<20));     // [56,64)
  short* P     = (short*)(ws);                   // ALIAS [0,64) — written by softmax, after all above are dead
  short* memT  = (short*)(ws + (64ull<<20));     // [64,72)     live through PV
  short* wqt_h = (short*)(ws + (72ull<<20));     // [72,74)
  short* wqt_l = (short*)(ws + (74ull<<20));     // [74,76)
  short* wo_b  = (short*)(ws + (76ull<<20));     // [76,78)
  short* retr  = (short*)(ws + (78ull<<20));     // [78,94)
  short* simh  = (short*)(ws + (94ull<<20));     // [94,158) fp16 logits
  char*  tail  = ws + (158ull<<20);
  float* biasM    = (float*)tail;
  float* surprise = (float*)(tail + (64<<10));
  float* top_vals = (float*)(tail + (128<<10));
  int*   top_idx  = (int*)  (tail + (129<<10));
  int*   slots    = (int*)  (tail + (130<<10));

  ln_kernel<<<NTOK, 256, 0, stream>>>(hs, gam, bet, nh, nl, surprise);
  topk_kernel<<<2, 256, 0, stream>>>(surprise, imp, top_vals, top_idx, slots);
  split_f32_kernel<<<4096, 256, 0, stream>>>(mem, mh, ml);
  transpose_split_kernel<<<dim3(32,32), 256, 0, stream>>>(Wq, wqt_h, wqt_l);
  tobf16_kernel<<<1024, 256, 0, stream>>>(Wo, wo_b);
  update_kernel<<<KTOP, 256, 0, stream>>>(top_vals, top_idx, slots, nh, nl, mh, ml);
  transpose_bf16_kernel<<<dim3(16,64), 256, 0, stream>>>(mh, memT);
  bias_kernel<<<1024, 256, 0, stream>>>(bq, mh, ml, biasM);
  // W2 = mem_upd @ Wq (split-3), out split hi/lo
  gemm128<1,0><<<dim3(8,32), 256, 0, stream>>>(
      mh, ml, wqt_h, wqt_l, H, H, w2h, w2l, nullptr, nullptr, nullptr);
  // sim = norm @ W2^T + biasM (split-3), out fp16
  gemm128<1,1><<<dim3(32,64), 256, 0, stream>>>(
      nh, nl, w2h, w2l, H, MMEM, simh, nullptr, nullptr, nullptr, biasM);
  // softmax rows -> P bf16 (normalized)
  softmax_kernel<<<NTOK, 256, 0, stream>>>(simh, P);
  // retr = P @ memT^T (plain bf16)
  gemm128<0,2><<<dim3(8,64), 256, 0, stream>>>(
      P, P, memT, memT, MMEM, H, retr, nullptr, nullptr, nullptr, nullptr);
  // out = hidden + retr @ Wo^T + bo
  gemm128<0,3><<<dim3(8,64), 256, 0, stream>>>(
      retr, retr, wo_b, wo_b, H, H, nullptr, nullptr, out, hs, bo);
}

// Round 3
// 515.030 us; speedup vs baseline: 3.9296x; 1.1509x over previous
//
#include <hip/hip_runtime.h>

#define H 1024
#define MMEM 4096
#define NTOK 8192
#define KTOP 64
#define FTHRESH 0.5f

typedef _Float16 half8 __attribute__((ext_vector_type(8)));  // 8 f16 in 4 VGPRs
typedef float vf4 __attribute__((ext_vector_type(4)));       // MFMA f32 acc
typedef short short8v __attribute__((ext_vector_type(8)));

__device__ __forceinline__ short f2h(float x){
  union { _Float16 h; short s; } u; u.h = (_Float16)x; return u.s;
}
__device__ __forceinline__ float h2f(short s){
  union { _Float16 h; short s; } u; u.s = s; return (float)u.h;
}

// async global->LDS, 16B/lane; LDS dest is wave-uniform base + lane*16 (HW rule)
__device__ __forceinline__ void gload_lds16(const short* g, short* l){
  __builtin_amdgcn_global_load_lds(
      (const __attribute__((address_space(1))) unsigned int*)g,
      (__attribute__((address_space(3))) unsigned int*)l, 16, 0, 0);
}

// ---------------- LayerNorm + surprise; outputs fp16 norm + fp32 norm ----------------
__global__ __launch_bounds__(256) void ln_kernel(
    const float* __restrict__ hs, const float* __restrict__ g, const float* __restrict__ be,
    short* __restrict__ n16, float* __restrict__ nF, float* __restrict__ surprise)
{
  int row = blockIdx.x, tid = threadIdx.x;
  long base = (long)row * H;
  float4 x = ((const float4*)(hs + base))[tid];
  float s1 = x.x + x.y + x.z + x.w;
  float s2 = x.x*x.x + x.y*x.y + x.z*x.z + x.w*x.w;
  __shared__ float r1[4], r2[4], r3[4];
  int w = tid >> 6, lane = tid & 63;
  for (int o = 32; o; o >>= 1){ s1 += __shfl_down(s1, o); s2 += __shfl_down(s2, o); }
  if (lane == 0){ r1[w] = s1; r2[w] = s2; }
  __syncthreads();
  float S1 = r1[0]+r1[1]+r1[2]+r1[3];
  float S2 = r2[0]+r2[1]+r2[2]+r2[3];
  float mean = S1 * (1.0f/H);
  float var  = S2 * (1.0f/H) - mean*mean;
  float rinv = rsqrtf(var + 1e-12f);
  float4 gg = ((const float4*)g)[tid];
  float4 bb = ((const float4*)be)[tid];
  float4 n;
  n.x = (x.x-mean)*rinv*gg.x + bb.x;
  n.y = (x.y-mean)*rinv*gg.y + bb.y;
  n.z = (x.z-mean)*rinv*gg.z + bb.z;
  n.w = (x.w-mean)*rinv*gg.w + bb.w;
  float sa = fabsf(n.x)+fabsf(n.y)+fabsf(n.z)+fabsf(n.w);
  for (int o = 32; o; o >>= 1) sa += __shfl_down(sa, o);
  if (lane == 0) r3[w] = sa;
  __syncthreads();
  if (tid == 0) surprise[row] = (r3[0]+r3[1]+r3[2]+r3[3]) * (1.0f/H);
  short4 h4;
  h4.x = f2h(n.x); h4.y = f2h(n.y); h4.z = f2h(n.z); h4.w = f2h(n.w);
  ((short4*)(n16 + base))[tid] = h4;
  ((float4*)(nF + base))[tid] = n;
}

// ---------------- register-resident top-K ----------------
// block 0: top-K of surprise (max, ties->lower idx). block 1: K smallest importance.
__global__ __launch_bounds__(256) void topk_kernel(
    const float* __restrict__ surprise, const float* __restrict__ imp,
    float* __restrict__ top_vals, int* __restrict__ top_idx, int* __restrict__ slots)
{
  int tid = threadIdx.x, w = tid >> 6, lane = tid & 63;
  int maxmode = (blockIdx.x == 0);
  int per = maxmode ? 32 : 16;
  const float* src = maxmode ? surprise : imp;
  float v[32];
  unsigned mask = maxmode ? 0xffffffffu : 0xffffu;
  #pragma unroll
  for (int j = 0; j < 32; ++j)
    if (j < per){ float x = src[tid + j*256]; v[j] = maxmode ? x : -x; }

  __shared__ float wv[4]; __shared__ int wi[4]; __shared__ int pub;
  for (int it = 0; it < KTOP; ++it){
    float best = -1e30f; int bi = 0x7fffffff;
    #pragma unroll
    for (int j = 0; j < 32; ++j){
      if (mask & (1u << j)){
        float x = v[j];
        if (x > best){ best = x; bi = tid + j*256; }
      }
    }
    for (int o = 32; o; o >>= 1){
      float ov = __shfl_down(best, o); int oi = __shfl_down(bi, o);
      if (ov > best || (ov == best && oi < bi)){ best = ov; bi = oi; }
    }
    if (lane == 0){ wv[w] = best; wi[w] = bi; }
    __syncthreads();
    if (tid == 0){
      float b = wv[0]; int bidx = wi[0];
      for (int q = 1; q < 4; ++q)
        if (wv[q] > b || (wv[q] == b && wi[q] < bidx)){ b = wv[q]; bidx = wi[q]; }
      if (maxmode){ top_vals[it] = b; top_idx[it] = bidx; }
      else slots[it] = bidx;
      pub = bidx;
    }
    __syncthreads();
    int widx = pub;
    if ((widx & 255) == tid) mask &= ~(1u << (widx >> 8));
  }
}

// ---------------- fp32 -> fp16 convert (float4 -> short4) ----------------
__global__ __launch_bounds__(256) void tof16_kernel(const float* __restrict__ in, short* __restrict__ out)
{
  long i = (long)blockIdx.x * 256 + threadIdx.x;
  float4 x = ((const float4*)in)[i];
  short4 h;
  h.x = f2h(x.x); h.y = f2h(x.y); h.z = f2h(x.z); h.w = f2h(x.w);
  ((short4*)out)[i] = h;
}

// ---------------- Wq fp32 [H][H] -> WqT fp16 hi/lo ----------------
__global__ __launch_bounds__(256) void transpose_split_kernel(
    const float* __restrict__ in, short* __restrict__ th_, short* __restrict__ tl_)
{
  __shared__ float t[32][33];
  int c0 = blockIdx.x*32, r0 = blockIdx.y*32;
  int tid = threadIdx.x;
  for (int k = 0; k < 4; ++k){
    int i = tid + k*256; int r = i >> 5, c = i & 31;
    t[r][c] = in[(long)(r0+r)*H + c0 + c];
  }
  __syncthreads();
  for (int k = 0; k < 4; ++k){
    int i = tid + k*256; int c = i >> 5, r = i & 31;
    float x = t[r][c];
    short hh = f2h(x);
    th_[(long)(c0+c)*H + r0 + r] = hh;
    tl_[(long)(c0+c)*H + r0 + r] = f2h(x - h2f(hh));
  }
}

// ---------------- apply top-K surprise writes into fp16 mem copy ----------------
__global__ __launch_bounds__(256) void update_kernel(
    const float* __restrict__ top_vals, const int* __restrict__ top_idx, const int* __restrict__ slots,
    const float* __restrict__ nF, short* __restrict__ m16)
{
  int i = blockIdx.x;
  if (top_vals[i] <= FTHRESH) return;
  int s = slots[i], r = top_idx[i];
  long so = (long)s*H, ro = (long)r*H;
  for (int h = threadIdx.x; h < H; h += 256) m16[so+h] = f2h(nF[ro+h]);
}

// ---------------- fp16 transpose m16 [MMEM][H] -> memT [H][MMEM] ----------------
__global__ __launch_bounds__(256) void transpose_f16_kernel(const short* __restrict__ in, short* __restrict__ out)
{
  __shared__ short t[64][65];
  int r0 = blockIdx.y*64, c0 = blockIdx.x*64;
  int tid = threadIdx.x;
  for (int k = 0; k < 16; ++k){
    int i = tid + k*256; int r = i >> 6, c = i & 63;
    t[r][c] = in[(long)(r0+r)*H + c0 + c];
  }
  __syncthreads();
  for (int k = 0; k < 16; ++k){
    int i = tid + k*256; int c = i >> 6, r = i & 63;
    out[(long)(c0+c)*MMEM + r0 + r] = t[r][c];
  }
}

// ---------------- biasM[m] = bq . mem_upd[m] ----------------
__global__ __launch_bounds__(256) void bias_kernel(
    const float* __restrict__ bq, const short* __restrict__ m16, float* __restrict__ biasM)
{
  int tid = threadIdx.x, w = tid >> 6, lane = tid & 63;
  int m = blockIdx.x*4 + w;
  const short* ph = m16 + (long)m*H;
  float s = 0.f;
  for (int j = 0; j < 16; ++j){
    int h = lane + j*64;
    s += bq[h] * h2f(ph[h]);
  }
  for (int o = 32; o; o >>= 1) s += __shfl_down(s, o);
  if (lane == 0) biasM[m] = s;
}

// ---------------- 128x128-tile fp16 GEMM: C[M][N] = A[M][K] * B[N][K]^T ----------------
// m97 recipe (BK=64, global_load_lds w16, 2 barriers/K-block) + XOR-8 LDS swizzle
// (chunk pos ^= row&7; applied on global source AND ds_read side -> 16-way conflicts -> 2-way).
// SPLIT: 0 = A,B single f16 (1 MFMA); 2 = A single, B fp16 hi/lo (2 MFMA compensated).
// MODE 0: C -> fp16 hi/lo.  1: C+biasN -> fp16.  2: C -> fp16.  3: C+resid+biasN -> fp32.
template<int SPLIT, int MODE>
__global__ __launch_bounds__(256) void gemm128(
    const short* __restrict__ A,
    const short* __restrict__ Bh, const short* __restrict__ Bl,
    int K, int N,
    short* __restrict__ O1, short* __restrict__ O2,
    float* __restrict__ Of, const float* __restrict__ resid, const float* __restrict__ biasN)
{
  __shared__ short sA[128*64];
  __shared__ short sBh[128*64];
  __shared__ short sBl[SPLIT ? 128*64 : 64];
  int tid = threadIdx.x, w = tid >> 6, lane = tid & 63, ln = lane & 15, quad = lane >> 4;
  int wr = w >> 1, wc = w & 1;
  long m0 = (long)blockIdx.y * 128, n0 = (long)blockIdx.x * 128;
  long Kl = K;
  vf4 acc[4][4];
  #pragma unroll
  for (int i = 0; i < 4; ++i) for (int j = 0; j < 4; ++j) for (int r = 0; r < 4; ++r) acc[i][j][r] = 0.0f;

  for (long kk = 0; kk < Kl; kk += 64){
    #pragma unroll
    for (int j = 0; j < 4; ++j){
      int f = (w*4 + j)*64 + lane;            // 16B-chunk id in [0,1024)
      int row = f >> 3, c8 = f & 7;
      long go = kk + (long)((c8 ^ (row & 7)) * 8);   // XOR-swizzled source chunk
      gload_lds16(A  + (m0+row)*Kl + go, sA  + (w*4+j)*512);
      gload_lds16(Bh + (n0+row)*Kl + go, sBh + (w*4+j)*512);
      if (SPLIT) gload_lds16(Bl + (n0+row)*Kl + go, sBl + (w*4+j)*512);
    }
    __syncthreads();
    #pragma unroll
    for (int ks = 0; ks < 64; ks += 32){
      int cbase = (ks >> 3) + quad;
      half8 bh[4], bl[4];
      #pragma unroll
      for (int j = 0; j < 4; ++j){
        int rb = wc*64 + j*16 + ln;
        int cb = cbase ^ (rb & 7);
        bh[j] = *(const half8*)&sBh[rb*64 + cb*8];
        if (SPLIT) bl[j] = *(const half8*)&sBl[rb*64 + cb*8];
      }
      #pragma unroll
      for (int i = 0; i < 4; ++i){
        int ra = wr*64 + i*16 + ln;
        int ca = cbase ^ (ra & 7);
        half8 a = *(const half8*)&sA[ra*64 + ca*8];
        #pragma unroll
        for (int j = 0; j < 4; ++j){
          acc[i][j] = __builtin_amdgcn_mfma_f32_16x16x32_f16(a, bh[j], acc[i][j], 0, 0, 0);
          if (SPLIT)
            acc[i][j] = __builtin_amdgcn_mfma_f32_16x16x32_f16(a, bl[j], acc[i][j], 0, 0, 0);
        }
      }
    }
    __syncthreads();
  }

  #pragma unroll
  for (int i = 0; i < 4; ++i){
    #pragma unroll
    for (int j = 0; j < 4; ++j){
      #pragma unroll
      for (int r = 0; r < 4; ++r){
        long row = m0 + wr*64 + i*16 + quad*4 + r;   // C/D: row=quad*4+reg, col=lane&15
        long col = n0 + wc*64 + j*16 + ln;
        float v = acc[i][j][r];
        if (MODE == 0){
          short hh = f2h(v);
          O1[row*(long)N + col] = hh;
          O2[row*(long)N + col] = f2h(v - h2f(hh));
        } else if (MODE == 1){
          O1[row*(long)N + col] = f2h(v + biasN[col]);
        } else if (MODE == 2){
          O1[row*(long)N + col] = f2h(v);
        } else {
          Of[row*(long)N + col] = v + resid[row*(long)N + col] + biasN[col];
        }
      }
    }
  }
}

// ---------------- row softmax in-place: sim fp16 [NTOK][MMEM] -> P fp16 ----------------
__global__ __launch_bounds__(256) void softmax_kernel(short* __restrict__ simP)
{
  long row = blockIdx.x;
  int tid = threadIdx.x, w = tid >> 6, lane = tid & 63;
  half8* ptr = (half8*)(simP + row*MMEM);
  float xf[16];
  float mx = -1e30f;
  #pragma unroll
  for (int j = 0; j < 2; ++j){
    half8 x = ptr[tid + j*256];
    #pragma unroll
    for (int e = 0; e < 8; ++e){ float f = (float)x[e]; xf[j*8+e] = f; mx = fmaxf(mx, f); }
  }
  for (int o = 32; o; o >>= 1) mx = fmaxf(mx, __shfl_xor(mx, o));
  __shared__ float rmax[4], rsum[4];
  if (lane == 0) rmax[w] = mx;
  __syncthreads();
  mx = fmaxf(fmaxf(rmax[0], rmax[1]), fmaxf(rmax[2], rmax[3]));
  float p[16], s = 0.f;
  #pragma unroll
  for (int k = 0; k < 16; ++k){ p[k] = __expf(xf[k] - mx); s += p[k]; }
  for (int o = 32; o; o >>= 1) s += __shfl_xor(s, o);
  if (lane == 0) rsum[w] = s;
  __syncthreads();
  float inv = 1.0f / (rsum[0]+rsum[1]+rsum[2]+rsum[3]);
  #pragma unroll
  for (int j = 0; j < 2; ++j){
    half8 o8;
    #pragma unroll
    for (int e = 0; e < 8; ++e) o8[e] = (_Float16)(p[j*8+e] * inv);
    ptr[tid + j*256] = o8;
  }
}

extern "C" void kernel_launch(void* const* d_in, const int* in_sizes, int n_in,
                              void* d_out, int out_size, void* d_ws, size_t ws_size,
                              hipStream_t stream)
{
  const float* hs  = (const float*)d_in[0];
  const float* gam = (const float*)d_in[1];
  const float* bet = (const float*)d_in[2];
  const float* Wq  = (const float*)d_in[3];
  const float* bq  = (const float*)d_in[4];
  const float* Wo  = (const float*)d_in[5];
  const float* bo  = (const float*)d_in[6];
  const float* mem = (const float*)d_in[7];
  const float* imp = (const float*)d_in[8];
  float* out = (float*)d_out;

  char* ws = (char*)d_ws;
  short* n16   = (short*)(ws);                   // [0,16)   fp16 norm; dead after sim
  short* w2h   = (short*)(ws + (16ull<<20));     // [16,24)  W2 fp16 hi
  short* w2l   = (short*)(ws + (24ull<<20));     // [24,32)  W2 fp16 lo
  short* memT  = (short*)(ws + (32ull<<20));     // [32,40)  mem_upd^T fp16
  short* simP  = (short*)(ws + (40ull<<20));     // [40,104) fp16 logits, softmax in-place -> P
  float* nF    = (float*)(ws + (104ull<<20));    // [104,136) fp32 norm; dead after update
  short* retr  = (short*)(ws + (104ull<<20));    // ALIAS [104,120) — live only after nF dead
  short* m16   = (short*)(ws + (136ull<<20));    // [136,144) fp16 mem (patched)
  short* wqt_h = (short*)(ws + (144ull<<20));    // [144,146)
  short* wqt_l = (short*)(ws + (146ull<<20));    // [146,148)
  short* wo16  = (short*)(ws + (148ull<<20));    // [148,150)
  char*  tail  = ws + (150ull<<20);
  float* biasM    = (float*)tail;
  float* surprise = (float*)(tail + (64<<10));
  float* top_vals = (float*)(tail + (128<<10));
  int*   top_idx  = (int*)  (tail + (129<<10));
  int*   slots    = (int*)  (tail + (130<<10));

  ln_kernel<<<NTOK, 256, 0, stream>>>(hs, gam, bet, n16, nF, surprise);
  topk_kernel<<<2, 256, 0, stream>>>(surprise, imp, top_vals, top_idx, slots);
  tof16_kernel<<<4096, 256, 0, stream>>>(mem, m16);                         // mem -> fp16
  transpose_split_kernel<<<dim3(32,32), 256, 0, stream>>>(Wq, wqt_h, wqt_l);
  tof16_kernel<<<1024, 256, 0, stream>>>(Wo, wo16);
  update_kernel<<<KTOP, 256, 0, stream>>>(top_vals, top_idx, slots, nF, m16);
  transpose_f16_kernel<<<dim3(16,64), 256, 0, stream>>>(m16, memT);
  bias_kernel<<<1024, 256, 0, stream>>>(bq, m16, biasM);
  // W2 = mem_upd @ Wq  (A single f16, B split f16 hi/lo), out fp16 hi/lo
  gemm128<2,0><<<dim3(8,32), 256, 0, stream>>>(
      m16, wqt_h, wqt_l, H, H, w2h, w2l, nullptr, nullptr, nullptr);
  // sim = norm @ W2^T + biasM  (A single f16, B split), out fp16
  gemm128<2,1><<<dim3(32,64), 256, 0, stream>>>(
      n16, w2h, w2l, H, MMEM, simP, nullptr, nullptr, nullptr, biasM);
  // softmax rows in-place -> P fp16 (normalized)
  softmax_kernel<<<NTOK, 256, 0, stream>>>(simP);
  // retr = P @ memT^T  (plain f16)
  gemm128<0,2><<<dim3(8,64), 256, 0, stream>>>(
      simP, memT, memT, MMEM, H, retr, nullptr, nullptr, nullptr, nullptr);
  // out = hidden + retr @ Wo^T + bo
  gemm128<0,3><<<dim3(8,64), 256, 0, stream>>>(
      retr, wo16, wo16, H, H, nullptr, nullptr, out, hs, bo);
}